// Round 13
// baseline (382.375 us; speedup 1.0000x reference)
//
#include <hip/hip_runtime.h>
#include <hip/hip_bf16.h>
#include <stdint.h>

#define T_   16
#define B_   512
#define IN_  3072
#define OUT_ 2048
#define NC_  10
#define M_   (T_ * B_)          // 8192

#define BM 128
#define BN 128

#define SPK_SZ ((size_t)T_ * B_ * OUT_)   // 16777216
#define CNT_SZ ((size_t)B_ * OUT_)        // 1048576 (= one t-plane)

#define TOL 6e-5
#define MAXFLAG (B_ * OUT_)

// tiled digit-array geometry: BK2=32, tile = 128 rows x 64 ushorts
// row layout: [32 hi bf16 | 32 lo bf16], 16B granules XOR-swizzled by row&7
// A rows are REORDERED: digit row m' = b*16 + t  (so a 128-row tile = 8 b x 16 t)
#define BK2   32
#define NCH2  (IN_ / BK2)       // 96
#define TILE_US 8192            // 128*64 ushorts = 16 KB
#define APAN (M_ / BM)          // 64
#define BPAN (OUT_ / BN)        // 16

#define A_PREP_BLOCKS (APAN * NCH2 * 2)   // 12288
#define B_PREP_BLOCKS (BPAN * NCH2 * 2)   // 3072

typedef __attribute__((ext_vector_type(8))) short s16x8;
typedef __attribute__((ext_vector_type(4))) float f32x4;
typedef __attribute__((ext_vector_type(16))) float f32x16;

__device__ unsigned int g_ctr;
__device__ unsigned int g_list[MAXFLAG];

__global__ void zero_ctr() { if (threadIdx.x == 0) g_ctr = 0; }

__device__ __forceinline__ unsigned short f2bf(float f) {
    __bf16 h = (__bf16)f;
    return *(unsigned short*)&h;
}
__device__ __forceinline__ float bf2f(unsigned short u) {
    union { unsigned int i; float f; } c; c.i = ((unsigned int)u) << 16; return c.f;
}
// ushort index into a [128][64]-ushort tile, 16B-granule XOR swizzle
__device__ __forceinline__ int swz8(int r, int g) {
    return r * 64 + ((g ^ (r & 7)) << 3);
}

__device__ __forceinline__ void gload_lds16(const void* g, void* l) {
    __builtin_amdgcn_global_load_lds(
        (const __attribute__((address_space(1))) unsigned int*)g,
        (__attribute__((address_space(3))) unsigned int*)l, 16, 0, 0);
}

// ---------------- prep: fp32 [rows][IN_] -> pre-swizzled digit tiles ----------------
__global__ __launch_bounds__(256)
void prep2(const float* __restrict__ x, const float* __restrict__ w,
           unsigned short* __restrict__ Adig, unsigned short* __restrict__ Bdig)
{
    if (blockIdx.x == 0 && threadIdx.x == 0) g_ctr = 0;

    const float* src; unsigned short* dst; int id; bool isA;
    if (blockIdx.x < A_PREP_BLOCKS) {
        src = x; dst = Adig; id = blockIdx.x * 256 + threadIdx.x; isA = true;
    } else {
        src = w; dst = Bdig; id = (blockIdx.x - A_PREP_BLOCKS) * 256 + threadIdx.x; isA = false;
    }
    const int gk = id & 3;
    const int r  = (id >> 2) & 127;
    const int ch = (id >> 9) % NCH2;
    const int pa = id / (NCH2 * 512);
    const int m  = pa * 128 + r;
    const int k  = ch * BK2 + gk * 8;

    // A reorder: digit row m = b*16 + t  ->  source row t*B + b
    size_t srow;
    if (isA) srow = (size_t)(m & 15) * B_ + (m >> 4);
    else     srow = (size_t)m;

    float f[8];
    *(float4*)&f[0] = *(const float4*)(src + srow * IN_ + k);
    *(float4*)&f[4] = *(const float4*)(src + srow * IN_ + k + 4);
    s16x8 hi, lo;
#pragma unroll
    for (int j = 0; j < 8; ++j) {
        unsigned short hb = f2bf(f[j]);
        hi[j] = (short)hb;
        lo[j] = (short)f2bf(f[j] - bf2f(hb));
    }
    unsigned short* tb = dst + ((size_t)pa * NCH2 + ch) * TILE_US;
    *(s16x8*)&tb[swz8(r, gk)]     = hi;
    *(s16x8*)&tb[swz8(r, gk + 4)] = lo;
}

// ---------------- main GEMM 256x256, 8 waves, 32x32x16 MFMA, reg pipeline ----------------
// LDS: SH[2 dbuf][4 regions][8192]  regions: 0=A-panel0 1=A-panel1 2=B-panel0 3=B-panel1
__global__ __launch_bounds__(512, 1)
void gemm_fused(const unsigned short* __restrict__ Adig,
                const unsigned short* __restrict__ Bdig,
                const float* __restrict__ fcb,
                float* __restrict__ out)
{
    __shared__ __align__(16) unsigned short SH[2 * 4 * TILE_US];  // 128 KB

    const int tid = threadIdx.x;
    const int l   = tid & 63;
    const int wv  = tid >> 6;          // wave 0..7
    const int wh  = wv >> 2;           // m-half (A panel) 0..1
    const int wn  = (wv & 3) * 64;     // n-offset within 256
    const int pB  = (wv >> 1) & 1;     // B panel this wave reads
    const int rb0 = (wv & 1) * 64;     // B row base within panel

    // XCD mapping: 256 blocks = 8 xcd x (4 m2 x 8 n2)
    const int lin = blockIdx.x;
    const int xcd = lin & 7;
    const int jj  = lin >> 3;          // 0..31
    const int pm2 = xcd * 4 + (jj & 3);   // 0..31 (256-row super-panel)
    const int pn2 = jj >> 2;              // 0..7  (256-col super-panel)
    const int n0  = pn2 * 256;

    f32x16 acc[4][2];
#pragma unroll
    for (int i = 0; i < 4; ++i)
#pragma unroll
        for (int j = 0; j < 2; ++j) acc[i][j] = (f32x16)0.0f;

    const int lr = l & 31;             // frag row within 32
    const int lh = l >> 5;             // k-half selector 0..1
    const int l8 = l * 8;              // lane 16B offset in ushorts

    // staging: wave wv stages region rg = wv>>1, half sub = wv&1 (8 gloads x 1KB)
    const int rg  = wv >> 1;
    const int sub = (wv & 1) * 4096;
    const unsigned short* gsrc0;
    if (rg < 2) gsrc0 = Adig + ((size_t)(2 * pm2 + rg) * NCH2) * TILE_US;
    else        gsrc0 = Bdig + ((size_t)(2 * pn2 + rg - 2) * NCH2) * TILE_US;

    auto stage = [&](int ch, int d) {
        const unsigned short* s = gsrc0 + (size_t)ch * TILE_US + sub;
        unsigned short* dp = SH + (d * 4 + rg) * TILE_US + sub;
#pragma unroll
        for (int i = 0; i < 8; ++i)
            gload_lds16(s + i * 512 + l8, dp + i * 512);
    };

    // frags: [kstep][frag]  (A: 4 x 32-row frags; B: 2 x 32-col frags)
    s16x8 a1f[2][4], a2f[2][4], b1f[2][2], b2f[2][2];

    auto a_read = [&](int dd, int ks, int i) {
        const unsigned short* Ap = SH + (dd * 4 + wh) * TILE_US;
        const int ra = i * 32 + lr;
        const int g  = 2 * ks + lh;
        a1f[ks][i] = *(const s16x8*)&Ap[swz8(ra, g)];
        a2f[ks][i] = *(const s16x8*)&Ap[swz8(ra, g + 4)];
    };
    auto b_read = [&](int dd, int ks, int j) {
        const unsigned short* Bp = SH + (dd * 4 + 2 + pB) * TILE_US;
        const int rb = rb0 + j * 32 + lr;
        const int g  = 2 * ks + lh;
        b1f[ks][j] = *(const s16x8*)&Bp[swz8(rb, g)];
        b2f[ks][j] = *(const s16x8*)&Bp[swz8(rb, g + 4)];
    };
    auto mfma3 = [&](int ks, int i, int j) {
        acc[i][j] = __builtin_amdgcn_mfma_f32_32x32x16_bf16(a1f[ks][i], b1f[ks][j], acc[i][j], 0, 0, 0);
        acc[i][j] = __builtin_amdgcn_mfma_f32_32x32x16_bf16(a2f[ks][i], b1f[ks][j], acc[i][j], 0, 0, 0);
        acc[i][j] = __builtin_amdgcn_mfma_f32_32x32x16_bf16(a1f[ks][i], b2f[ks][j], acc[i][j], 0, 0, 0);
    };

    // MFMA phase (chunk ch, frags in regs) with interleaved reload from buf dd
    auto phase_reload = [&](int dd) {
        __builtin_amdgcn_s_setprio(1);
#pragma unroll
        for (int i = 0; i < 4; ++i) {
#pragma unroll
            for (int ks = 0; ks < 2; ++ks)
#pragma unroll
                for (int j = 0; j < 2; ++j) mfma3(ks, i, j);
            a_read(dd, 0, i);          // a[*][i] dead for this chunk -> reload
            a_read(dd, 1, i);
        }
        b_read(dd, 0, 0); b_read(dd, 0, 1);
        b_read(dd, 1, 0); b_read(dd, 1, 1);
        __builtin_amdgcn_s_setprio(0);
    };
    auto phase_plain = [&]() {
        __builtin_amdgcn_s_setprio(1);
#pragma unroll
        for (int i = 0; i < 4; ++i)
#pragma unroll
            for (int ks = 0; ks < 2; ++ks)
#pragma unroll
                for (int j = 0; j < 2; ++j) mfma3(ks, i, j);
        __builtin_amdgcn_s_setprio(0);
    };

    auto body = [&](int ch, int d, int dd) {
        asm volatile("s_waitcnt lgkmcnt(0)" ::: "memory");   // my reads of buf d done
        __builtin_amdgcn_s_barrier();                        // all waves done with buf d
        asm volatile("" ::: "memory");
        if (ch + 2 < NCH2) {
            stage(ch + 2, d);                                // overwrite buf d; 16 outstanding
            asm volatile("s_waitcnt vmcnt(8)" ::: "memory"); // stage(ch+1) (buf dd) landed
        } else {
            asm volatile("s_waitcnt vmcnt(0)" ::: "memory"); // tail drain
        }
        __builtin_amdgcn_s_barrier();                        // buf dd visible to all
        asm volatile("" ::: "memory");
        if (ch + 1 < NCH2) phase_reload(dd); else phase_plain();
    };

    // prologue: fill buf0, read chunk-0 frags, launch stage(1)
    stage(0, 0);
    asm volatile("s_waitcnt vmcnt(0)" ::: "memory");
    __builtin_amdgcn_s_barrier();
    asm volatile("" ::: "memory");
    stage(1, 1);
#pragma unroll
    for (int i = 0; i < 4; ++i) { a_read(0, 0, i); a_read(0, 1, i); }
#pragma unroll
    for (int ks = 0; ks < 2; ++ks) { b_read(0, ks, 0); b_read(0, ks, 1); }

    for (int c2 = 0; c2 < NCH2 / 2; ++c2) {
        const int ch = c2 * 2;
        body(ch, 0, 1);
        body(ch + 1, 1, 0);
    }

    // ---- fused epilogue: two 128-row passes through LDS, LIF in fp64 ----
    float* cf = (float*)SH;   // [128][256] floats = 128 KB; col ^ ((row&12)<<1)

    const int o_l = tid & 255;
    const int o   = n0 + o_l;
    const double bias = (double)fcb[o];
    const int bq0 = (tid >> 8) * 4;    // 0 or 4

    for (int p = 0; p < 2; ++p) {
        if (p) __syncthreads();        // pass-0 reads done before overwrite
        if (wh == p) {
            // 32x32 C/D layout: o-col = lane&31, m-row = (reg&3)+8*(reg>>2)+4*(lane>>5)
#pragma unroll
            for (int i = 0; i < 4; ++i)
#pragma unroll
                for (int j = 0; j < 2; ++j)
#pragma unroll
                    for (int reg = 0; reg < 16; ++reg) {
                        const int row = i * 32 + (reg & 3) + 8 * (reg >> 2) + 4 * lh;
                        const int col = wn + j * 32 + lr;
                        cf[row * 256 + (col ^ ((row & 12) << 1))] = acc[i][j][reg];
                    }
        }
        __syncthreads();

#pragma unroll
        for (int q = 0; q < 4; ++q) {
            const int rl = bq0 + q;            // 0..7 within pass
            const int b  = pm2 * 16 + p * 8 + rl;
            double v = 0.0; int cnt = 0; bool fl = false;
#pragma unroll
            for (int t = 0; t < T_; ++t) {
                const int row = rl * 16 + t;
                const float c32 = cf[row * 256 + (o_l ^ ((row & 12) << 1))];
                const double c = (double)c32 + bias;
                v = v + (c - v) * 0.5;
                const double dlt = v - 1.0;
                const bool s = dlt >= 0.0;
                if (fabs(dlt) < TOL) fl = true;
                out[(size_t)t * CNT_SZ + (size_t)b * OUT_ + o] = s ? 1.0f : 0.0f;
                cnt += s ? 1 : 0;
                if (s) v = 0.0;
            }
            out[SPK_SZ + (size_t)b * OUT_ + o] = (float)cnt;
            if (fl) {
                unsigned int idx = atomicAdd(&g_ctr, 1u);
                if (idx < MAXFLAG) g_list[idx] = (unsigned int)(b * OUT_ + o);
            }
        }
    }
}

// ---------------- fallback GEMM (round-4, proven): in-kernel conversion ----------------
__global__ __launch_bounds__(256, 2)
void gemm_split(const float* __restrict__ x, const float* __restrict__ w,
                float* __restrict__ cur)
{
    __shared__ __align__(16) unsigned short A1[BM * 64];
    __shared__ __align__(16) unsigned short A2[BM * 64];
    __shared__ __align__(16) unsigned short B1[BN * 64];
    __shared__ __align__(16) unsigned short B2[BN * 64];

    const int tid = threadIdx.x;
    const int l   = tid & 63;
    const int wv  = tid >> 6;
    const int wm  = (wv >> 1) * 64;
    const int wn  = (wv & 1) * 64;
    const int m0  = blockIdx.x * BM;
    const int n0  = blockIdx.y * BN;

    const int r = tid >> 1;
    const int h = tid & 1;
    const float* xa = x + (size_t)(m0 + r) * IN_ + h * 32;
    const float* wa = w + (size_t)(n0 + r) * IN_ + h * 32;

    f32x4 acc[4][4];
#pragma unroll
    for (int i = 0; i < 4; ++i)
#pragma unroll
        for (int j = 0; j < 4; ++j) acc[i][j] = (f32x4)0.0f;

    const int lp = l & 15;
    const int lq = l >> 4;

    for (int ch = 0; ch < 48; ++ch) {
        const int k0 = ch * 64;
        __syncthreads();
        float fx[32], fw[32];
#pragma unroll
        for (int i = 0; i < 8; ++i)
            *(float4*)&fx[4 * i] = *(const float4*)(xa + k0 + 4 * i);
#pragma unroll
        for (int i = 0; i < 8; ++i)
            *(float4*)&fw[4 * i] = *(const float4*)(wa + k0 + 4 * i);

#pragma unroll
        for (int q = 0; q < 4; ++q) {
            s16x8 vh, vl, uh, ul;
#pragma unroll
            for (int j = 0; j < 8; ++j) {
                float f = fx[8 * q + j];
                unsigned short hb = f2bf(f);
                vh[j] = (short)hb;
                vl[j] = (short)f2bf(f - bf2f(hb));
                float g = fw[8 * q + j];
                unsigned short gb = f2bf(g);
                uh[j] = (short)gb;
                ul[j] = (short)f2bf(g - bf2f(gb));
            }
            const int gg = h * 4 + q;
            *(s16x8*)&A1[swz8(r, gg)] = vh;
            *(s16x8*)&A2[swz8(r, gg)] = vl;
            *(s16x8*)&B1[swz8(r, gg)] = uh;
            *(s16x8*)&B2[swz8(r, gg)] = ul;
        }
        __syncthreads();

#pragma unroll
        for (int kk = 0; kk < 2; ++kk) {
            const int gb = kk * 4 + lq;
            s16x8 a1f[4], a2f[4], b1f[4], b2f[4];
#pragma unroll
            for (int i = 0; i < 4; ++i) {
                const int ra = wm + i * 16 + lp;
                a1f[i] = *(const s16x8*)&A1[swz8(ra, gb)];
                a2f[i] = *(const s16x8*)&A2[swz8(ra, gb)];
                const int rb = wn + i * 16 + lp;
                b1f[i] = *(const s16x8*)&B1[swz8(rb, gb)];
                b2f[i] = *(const s16x8*)&B2[swz8(rb, gb)];
            }
#pragma unroll
            for (int i = 0; i < 4; ++i)
#pragma unroll
                for (int j = 0; j < 4; ++j) {
                    acc[i][j] = __builtin_amdgcn_mfma_f32_16x16x32_bf16(
                        a1f[i], b1f[j], acc[i][j], 0, 0, 0);
                    acc[i][j] = __builtin_amdgcn_mfma_f32_16x16x32_bf16(
                        a2f[i], b1f[j], acc[i][j], 0, 0, 0);
                    acc[i][j] = __builtin_amdgcn_mfma_f32_16x16x32_bf16(
                        a1f[i], b2f[j], acc[i][j], 0, 0, 0);
                }
        }
    }

    const int crow = lq * 4, ccol = lp;
#pragma unroll
    for (int i = 0; i < 4; ++i)
#pragma unroll
        for (int j = 0; j < 4; ++j) {
            const size_t mbase = (size_t)(m0 + wm + i * 16 + crow);
            const int o = n0 + wn + j * 16 + ccol;
#pragma unroll
            for (int reg = 0; reg < 4; ++reg)
                cur[(mbase + reg) * OUT_ + o] = acc[i][j][reg];
        }
}

// LIF recurrence over T in fp64 (fallback path only)
__global__ __launch_bounds__(256)
void lif_pass(const float* __restrict__ fcb, float* __restrict__ out)
{
    const int idx = blockIdx.x * 256 + threadIdx.x;   // b*OUT + o
    const int o = idx & (OUT_ - 1);
    const double bias = (double)fcb[o];
    double v = 0.0; int cnt = 0; bool fl = false;
#pragma unroll
    for (int t = 0; t < T_; ++t) {
        const size_t p = (size_t)t * CNT_SZ + idx;
        double c = (double)out[p] + bias;
        v = v + (c - v) * 0.5;
        double d = v - 1.0;
        bool s = d >= 0.0;
        if (fabs(d) < TOL) fl = true;
        out[p] = s ? 1.0f : 0.0f;
        cnt += s ? 1 : 0;
        if (s) v = 0.0;
    }
    out[SPK_SZ + idx] = (float)cnt;
    if (fl) {
        unsigned int pI = atomicAdd(&g_ctr, 1u);
        if (pI < MAXFLAG) g_list[pI] = (unsigned int)idx;
    }
}

// fp64 recompute of flagged neurons (one wave per neuron)
__global__ void fixup(const float* __restrict__ x, const float* __restrict__ w,
                      const float* __restrict__ fcb, float* __restrict__ out)
{
    int nf = (int)g_ctr; if (nf > MAXFLAG) nf = MAXFLAG;
    const int lane = threadIdx.x & 63;
    const int wid  = (blockIdx.x * blockDim.x + threadIdx.x) >> 6;
    const int nw   = (gridDim.x * blockDim.x) >> 6;

    for (int i = wid; i < nf; i += nw) {
        unsigned int e = g_list[i];
        int b = (int)(e >> 11), o = (int)(e & (OUT_ - 1));
        double part[T_];
#pragma unroll
        for (int t = 0; t < T_; ++t) part[t] = 0.0;
        const float* wrow = w + (size_t)o * IN_;
        for (int k = lane; k < IN_; k += 64) {
            double wvv = (double)wrow[k];
#pragma unroll
            for (int t = 0; t < T_; ++t)
                part[t] = fma((double)x[((size_t)t * B_ + b) * IN_ + k], wvv, part[t]);
        }
#pragma unroll
        for (int t = 0; t < T_; ++t)
#pragma unroll
            for (int off = 32; off > 0; off >>= 1)
                part[t] += __shfl_xor(part[t], off, 64);
        if (lane == 0) {
            double bias = (double)fcb[o];
            double v = 0.0; int cnt = 0;
#pragma unroll
            for (int t = 0; t < T_; ++t) {
                double c = part[t] + bias;
                v = v + (c - v) * 0.5;
                bool s = (v - 1.0) >= 0.0;
                out[(size_t)t * CNT_SZ + (size_t)b * OUT_ + o] = s ? 1.0f : 0.0f;
                cnt += s ? 1 : 0;
                if (s) v = 0.0;
            }
            out[SPK_SZ + (size_t)b * OUT_ + o] = (float)cnt;
        }
    }
}

// logits[b][c] = sum_o count[b][o] * aux_w[c][o] + aux_b[c]
__global__ void aux_logits(const float* __restrict__ cnt,
                           const float* __restrict__ aw,
                           const float* __restrict__ ab,
                           float* __restrict__ lg)
{
    const int b = blockIdx.x;
    const int lane = threadIdx.x;  // 64 threads = 1 wave
    double p0=0,p1=0,p2=0,p3=0,p4=0,p5=0,p6=0,p7=0,p8=0,p9=0;
    for (int o = lane; o < OUT_; o += 64) {
        double c = (double)cnt[(size_t)b * OUT_ + o];
        p0 = fma(c, (double)aw[0 * OUT_ + o], p0);
        p1 = fma(c, (double)aw[1 * OUT_ + o], p1);
        p2 = fma(c, (double)aw[2 * OUT_ + o], p2);
        p3 = fma(c, (double)aw[3 * OUT_ + o], p3);
        p4 = fma(c, (double)aw[4 * OUT_ + o], p4);
        p5 = fma(c, (double)aw[5 * OUT_ + o], p5);
        p6 = fma(c, (double)aw[6 * OUT_ + o], p6);
        p7 = fma(c, (double)aw[7 * OUT_ + o], p7);
        p8 = fma(c, (double)aw[8 * OUT_ + o], p8);
        p9 = fma(c, (double)aw[9 * OUT_ + o], p9);
    }
#pragma unroll
    for (int off = 32; off > 0; off >>= 1) {
        p0 += __shfl_xor(p0, off, 64); p1 += __shfl_xor(p1, off, 64);
        p2 += __shfl_xor(p2, off, 64); p3 += __shfl_xor(p3, off, 64);
        p4 += __shfl_xor(p4, off, 64); p5 += __shfl_xor(p5, off, 64);
        p6 += __shfl_xor(p6, off, 64); p7 += __shfl_xor(p7, off, 64);
        p8 += __shfl_xor(p8, off, 64); p9 += __shfl_xor(p9, off, 64);
    }
    if (lane == 0) {
        double pv[NC_] = {p0,p1,p2,p3,p4,p5,p6,p7,p8,p9};
#pragma unroll
        for (int c = 0; c < NC_; ++c)
            lg[(size_t)b * NC_ + c] = (float)(pv[c] + (double)ab[c]);
    }
}

extern "C" void kernel_launch(void* const* d_in, const int* in_sizes, int n_in,
                              void* d_out, int out_size, void* d_ws, size_t ws_size,
                              hipStream_t stream)
{
    (void)in_sizes; (void)n_in; (void)out_size;
    const float* x   = (const float*)d_in[0];
    const float* w   = (const float*)d_in[1];
    const float* fcb = (const float*)d_in[2];
    const float* aw  = (const float*)d_in[3];
    const float* ab  = (const float*)d_in[4];
    float* out = (float*)d_out;

    const size_t needA = (size_t)APAN * NCH2 * TILE_US * 2;  // 100.7 MB
    const size_t needB = (size_t)BPAN * NCH2 * TILE_US * 2;  // 25.2 MB

    if (ws_size >= needA + needB) {
        unsigned short* Adig = (unsigned short*)d_ws;
        unsigned short* Bdig = Adig + (size_t)APAN * NCH2 * TILE_US;
        prep2<<<dim3(A_PREP_BLOCKS + B_PREP_BLOCKS), dim3(256), 0, stream>>>(
            x, w, Adig, Bdig);
        gemm_fused<<<dim3(256), dim3(512), 0, stream>>>(Adig, Bdig, fcb, out);
    } else {
        zero_ctr<<<dim3(1), dim3(64), 0, stream>>>();
        gemm_split<<<dim3(M_ / BM, OUT_ / BN), dim3(256), 0, stream>>>(x, w, out);
        lif_pass<<<dim3(CNT_SZ / 256), dim3(256), 0, stream>>>(fcb, out);
    }

    fixup<<<dim3(512), dim3(256), 0, stream>>>(x, w, fcb, out);

    aux_logits<<<dim3(B_), dim3(64), 0, stream>>>(
        out + SPK_SZ, aw, ab, out + SPK_SZ + CNT_SZ);
}

// Round 14
// 346.378 us; speedup vs baseline: 1.1039x; 1.1039x over previous
//
#include <hip/hip_runtime.h>
#include <hip/hip_bf16.h>
#include <stdint.h>

#define T_   16
#define B_   512
#define IN_  3072
#define OUT_ 2048
#define NC_  10
#define M_   (T_ * B_)          // 8192

#define BM 128
#define BN 128

#define SPK_SZ ((size_t)T_ * B_ * OUT_)   // 16777216
#define CNT_SZ ((size_t)B_ * OUT_)        // 1048576 (= one t-plane)

#define TOL 6e-5
#define MAXFLAG (B_ * OUT_)

// tiled digit-array geometry: BK2=32, tile = 128 rows x 64 ushorts
// row layout: [32 hi bf16 | 32 lo bf16], 16B granules XOR-swizzled by row&7
// A rows are REORDERED: digit row m' = b*16 + t  (so a 128-row tile = 8 b x 16 t)
#define BK2   32
#define NCH2  (IN_ / BK2)       // 96
#define TILE_US 8192            // 128*64 ushorts = 16 KB
#define APAN (M_ / BM)          // 64
#define BPAN (OUT_ / BN)        // 16

#define A_PREP_BLOCKS (APAN * NCH2 * 2)   // 12288
#define B_PREP_BLOCKS (BPAN * NCH2 * 2)   // 3072

typedef __attribute__((ext_vector_type(8))) short s16x8;
typedef __attribute__((ext_vector_type(4))) float f32x4;

__device__ unsigned int g_ctr;
__device__ unsigned int g_list[MAXFLAG];

__global__ void zero_ctr() { if (threadIdx.x == 0) g_ctr = 0; }

__device__ __forceinline__ unsigned short f2bf(float f) {
    __bf16 h = (__bf16)f;
    return *(unsigned short*)&h;
}
__device__ __forceinline__ float bf2f(unsigned short u) {
    union { unsigned int i; float f; } c; c.i = ((unsigned int)u) << 16; return c.f;
}
// ushort index into a [128][64]-ushort tile, 16B-granule XOR swizzle
__device__ __forceinline__ int swz8(int r, int g) {
    return r * 64 + ((g ^ (r & 7)) << 3);
}

__device__ __forceinline__ void gload_lds16(const void* g, void* l) {
    __builtin_amdgcn_global_load_lds(
        (const __attribute__((address_space(1))) unsigned int*)g,
        (__attribute__((address_space(3))) unsigned int*)l, 16, 0, 0);
}

// ---------------- prep: fp32 [rows][IN_] -> pre-swizzled digit tiles ----------------
__global__ __launch_bounds__(256)
void prep2(const float* __restrict__ x, const float* __restrict__ w,
           unsigned short* __restrict__ Adig, unsigned short* __restrict__ Bdig)
{
    if (blockIdx.x == 0 && threadIdx.x == 0) g_ctr = 0;

    const float* src; unsigned short* dst; int id; bool isA;
    if (blockIdx.x < A_PREP_BLOCKS) {
        src = x; dst = Adig; id = blockIdx.x * 256 + threadIdx.x; isA = true;
    } else {
        src = w; dst = Bdig; id = (blockIdx.x - A_PREP_BLOCKS) * 256 + threadIdx.x; isA = false;
    }
    const int gk = id & 3;
    const int r  = (id >> 2) & 127;
    const int ch = (id >> 9) % NCH2;
    const int pa = id / (NCH2 * 512);
    const int m  = pa * 128 + r;
    const int k  = ch * BK2 + gk * 8;

    // A reorder: digit row m = b*16 + t  ->  source row t*B + b
    size_t srow;
    if (isA) srow = (size_t)(m & 15) * B_ + (m >> 4);
    else     srow = (size_t)m;

    float f[8];
    *(float4*)&f[0] = *(const float4*)(src + srow * IN_ + k);
    *(float4*)&f[4] = *(const float4*)(src + srow * IN_ + k + 4);
    s16x8 hi, lo;
#pragma unroll
    for (int j = 0; j < 8; ++j) {
        unsigned short hb = f2bf(f[j]);
        hi[j] = (short)hb;
        lo[j] = (short)f2bf(f[j] - bf2f(hb));
    }
    unsigned short* tb = dst + ((size_t)pa * NCH2 + ch) * TILE_US;
    *(s16x8*)&tb[swz8(r, gk)]     = hi;
    *(s16x8*)&tb[swz8(r, gk + 4)] = lo;
}

// ---------------- main GEMM 256x256, 8 waves, register-frag pipeline ----------------
// LDS: SH[2 dbuf][4 regions][8192]  regions: 0=A-panel0 1=A-panel1 2=B-panel0 3=B-panel1
__global__ __launch_bounds__(512, 1)
void gemm_fused(const unsigned short* __restrict__ Adig,
                const unsigned short* __restrict__ Bdig,
                const float* __restrict__ fcb,
                float* __restrict__ out)
{
    __shared__ __align__(16) unsigned short SH[2 * 4 * TILE_US];  // 128 KB

    const int tid = threadIdx.x;
    const int l   = tid & 63;
    const int wv  = tid >> 6;          // wave 0..7
    const int wh  = wv >> 2;           // m-half (A panel) 0..1
    const int wn  = (wv & 3) * 64;     // n-offset within 256
    const int pB  = (wv >> 1) & 1;     // B panel this wave reads
    const int rb0 = (wv & 1) * 64;     // B row base within panel

    // XCD mapping: 256 blocks = 8 xcd x (4 m2 x 8 n2)
    const int lin = blockIdx.x;
    const int xcd = lin & 7;
    const int jj  = lin >> 3;          // 0..31
    const int pm2 = xcd * 4 + (jj & 3);   // 0..31 (256-row super-panel)
    const int pn2 = jj >> 2;              // 0..7  (256-col super-panel)
    const int n0  = pn2 * 256;

    f32x4 acc[8][4];
#pragma unroll
    for (int i = 0; i < 8; ++i)
#pragma unroll
        for (int j = 0; j < 4; ++j) acc[i][j] = (f32x4)0.0f;

    const int lp = l & 15;             // frag row within 16
    const int lq = l >> 4;             // frag k-granule 0..3
    const int l8 = l * 8;              // lane 16B offset in ushorts

    // staging: wave wv stages region rg = wv>>1, half sub = wv&1 (8 gloads x 1KB)
    const int rg  = wv >> 1;
    const int sub = (wv & 1) * 4096;
    const unsigned short* gsrc0;
    if (rg < 2) gsrc0 = Adig + ((size_t)(2 * pm2 + rg) * NCH2) * TILE_US;
    else        gsrc0 = Bdig + ((size_t)(2 * pn2 + rg - 2) * NCH2) * TILE_US;

    auto stage = [&](int ch, int d) {
        const unsigned short* s = gsrc0 + (size_t)ch * TILE_US + sub;
        unsigned short* dp = SH + (d * 4 + rg) * TILE_US + sub;
#pragma unroll
        for (int i = 0; i < 8; ++i)
            gload_lds16(s + i * 512 + l8, dp + i * 512);
    };

    s16x8 a1f[8], a2f[8], b1f[4], b2f[4];

    auto a_read = [&](int dd, int i) {
        const int ra = i * 16 + lp;
        const unsigned short* Ap = SH + (dd * 4 + wh) * TILE_US;
        a1f[i] = *(const s16x8*)&Ap[swz8(ra, lq)];
        a2f[i] = *(const s16x8*)&Ap[swz8(ra, lq + 4)];
    };
    auto b_read = [&](int dd, int j) {
        const int rb = rb0 + j * 16 + lp;
        const unsigned short* Bp = SH + (dd * 4 + 2 + pB) * TILE_US;
        b1f[j] = *(const s16x8*)&Bp[swz8(rb, lq)];
        b2f[j] = *(const s16x8*)&Bp[swz8(rb, lq + 4)];
    };
    auto mfma3 = [&](int i, int j) {
        acc[i][j] = __builtin_amdgcn_mfma_f32_16x16x32_bf16(a1f[i], b1f[j], acc[i][j], 0, 0, 0);
        acc[i][j] = __builtin_amdgcn_mfma_f32_16x16x32_bf16(a2f[i], b1f[j], acc[i][j], 0, 0, 0);
        acc[i][j] = __builtin_amdgcn_mfma_f32_16x16x32_bf16(a1f[i], b2f[j], acc[i][j], 0, 0, 0);
    };

    // MFMA phase with interleaved reload of next chunk's frags from buf dd
    auto phase_reload = [&](int dd) {
        __builtin_amdgcn_s_setprio(1);
#pragma unroll
        for (int i = 0; i < 7; ++i) {
#pragma unroll
            for (int j = 0; j < 4; ++j) mfma3(i, j);
            a_read(dd, i);             // a[i] dead for this chunk -> reload in place
        }
#pragma unroll
        for (int j = 0; j < 4; ++j) {
            mfma3(7, j);
            b_read(dd, j);             // b[j] last used at i=7 -> reload in place
        }
        a_read(dd, 7);
        __builtin_amdgcn_s_setprio(0);
    };
    auto phase_plain = [&]() {
        __builtin_amdgcn_s_setprio(1);
#pragma unroll
        for (int i = 0; i < 8; ++i)
#pragma unroll
            for (int j = 0; j < 4; ++j) mfma3(i, j);
        __builtin_amdgcn_s_setprio(0);
    };

    auto body = [&](int ch, int d, int dd) {
        asm volatile("s_waitcnt lgkmcnt(0)" ::: "memory");   // my reads of buf d done
        __builtin_amdgcn_s_barrier();                        // all waves done with buf d
        asm volatile("" ::: "memory");
        if (ch + 2 < NCH2) {
            stage(ch + 2, d);                                // overwrite buf d; 16 outstanding
            asm volatile("s_waitcnt vmcnt(8)" ::: "memory"); // stage(ch+1) (buf dd) landed
        } else {
            asm volatile("s_waitcnt vmcnt(0)" ::: "memory"); // tail drain
        }
        __builtin_amdgcn_s_barrier();                        // buf dd visible to all
        asm volatile("" ::: "memory");
        if (ch + 1 < NCH2) phase_reload(dd); else phase_plain();
    };

    // prologue: fill buf0, read chunk-0 frags, launch stage(1)
    stage(0, 0);
    asm volatile("s_waitcnt vmcnt(0)" ::: "memory");
    __builtin_amdgcn_s_barrier();
    asm volatile("" ::: "memory");
    stage(1, 1);
#pragma unroll
    for (int i = 0; i < 8; ++i) a_read(0, i);
#pragma unroll
    for (int j = 0; j < 4; ++j) b_read(0, j);

    for (int c2 = 0; c2 < NCH2 / 2; ++c2) {
        const int ch = c2 * 2;
        body(ch, 0, 1);
        body(ch + 1, 1, 0);
    }

    // ---- fused epilogue: two 128-row passes through LDS, LIF in fp32 ----
    // (fp32 LIF error <= ~2e-7 << TOL; near-threshold neurons are flagged
    //  and recomputed in fp64 by fixup, so decisions stay exact.)
    float* cf = (float*)SH;   // [128][256] floats = 128 KB; col ^ ((row&12)<<1)

    const int o_l = tid & 255;
    const int o   = n0 + o_l;
    const float bias = fcb[o];
    const int bq0 = (tid >> 8) * 4;    // 0 or 4

    for (int p = 0; p < 2; ++p) {
        if (p) __syncthreads();        // pass-0 reads done before overwrite
        if (wh == p) {
#pragma unroll
            for (int i = 0; i < 8; ++i)
#pragma unroll
                for (int j = 0; j < 4; ++j)
#pragma unroll
                    for (int reg = 0; reg < 4; ++reg) {
                        const int row = i * 16 + lq * 4 + reg;
                        const int col = wn + j * 16 + lp;
                        cf[row * 256 + (col ^ ((row & 12) << 1))] = acc[i][j][reg];
                    }
        }
        __syncthreads();

#pragma unroll
        for (int q = 0; q < 4; ++q) {
            const int rl = bq0 + q;            // 0..7 within pass
            const int b  = pm2 * 16 + p * 8 + rl;
            float v = 0.0f; int cnt = 0; bool fl = false;
#pragma unroll
            for (int t = 0; t < T_; ++t) {
                const int row = rl * 16 + t;
                const float c32 = cf[row * 256 + (o_l ^ ((row & 12) << 1))];
                const float c = c32 + bias;
                v = v + (c - v) * 0.5f;
                const float dlt = v - 1.0f;
                const bool s = dlt >= 0.0f;
                if (fabsf(dlt) < (float)TOL) fl = true;
                out[(size_t)t * CNT_SZ + (size_t)b * OUT_ + o] = s ? 1.0f : 0.0f;
                cnt += s ? 1 : 0;
                if (s) v = 0.0f;
            }
            out[SPK_SZ + (size_t)b * OUT_ + o] = (float)cnt;
            if (fl) {
                unsigned int idx = atomicAdd(&g_ctr, 1u);
                if (idx < MAXFLAG) g_list[idx] = (unsigned int)(b * OUT_ + o);
            }
        }
    }
}

// ---------------- fallback GEMM (round-4, proven): in-kernel conversion ----------------
__global__ __launch_bounds__(256, 2)
void gemm_split(const float* __restrict__ x, const float* __restrict__ w,
                float* __restrict__ cur)
{
    __shared__ __align__(16) unsigned short A1[BM * 64];
    __shared__ __align__(16) unsigned short A2[BM * 64];
    __shared__ __align__(16) unsigned short B1[BN * 64];
    __shared__ __align__(16) unsigned short B2[BN * 64];

    const int tid = threadIdx.x;
    const int l   = tid & 63;
    const int wv  = tid >> 6;
    const int wm  = (wv >> 1) * 64;
    const int wn  = (wv & 1) * 64;
    const int m0  = blockIdx.x * BM;
    const int n0  = blockIdx.y * BN;

    const int r = tid >> 1;
    const int h = tid & 1;
    const float* xa = x + (size_t)(m0 + r) * IN_ + h * 32;
    const float* wa = w + (size_t)(n0 + r) * IN_ + h * 32;

    f32x4 acc[4][4];
#pragma unroll
    for (int i = 0; i < 4; ++i)
#pragma unroll
        for (int j = 0; j < 4; ++j) acc[i][j] = (f32x4)0.0f;

    const int lp = l & 15;
    const int lq = l >> 4;

    for (int ch = 0; ch < 48; ++ch) {
        const int k0 = ch * 64;
        __syncthreads();
        float fx[32], fw[32];
#pragma unroll
        for (int i = 0; i < 8; ++i)
            *(float4*)&fx[4 * i] = *(const float4*)(xa + k0 + 4 * i);
#pragma unroll
        for (int i = 0; i < 8; ++i)
            *(float4*)&fw[4 * i] = *(const float4*)(wa + k0 + 4 * i);

#pragma unroll
        for (int q = 0; q < 4; ++q) {
            s16x8 vh, vl, uh, ul;
#pragma unroll
            for (int j = 0; j < 8; ++j) {
                float f = fx[8 * q + j];
                unsigned short hb = f2bf(f);
                vh[j] = (short)hb;
                vl[j] = (short)f2bf(f - bf2f(hb));
                float g = fw[8 * q + j];
                unsigned short gb = f2bf(g);
                uh[j] = (short)gb;
                ul[j] = (short)f2bf(g - bf2f(gb));
            }
            const int gg = h * 4 + q;
            *(s16x8*)&A1[swz8(r, gg)] = vh;
            *(s16x8*)&A2[swz8(r, gg)] = vl;
            *(s16x8*)&B1[swz8(r, gg)] = uh;
            *(s16x8*)&B2[swz8(r, gg)] = ul;
        }
        __syncthreads();

#pragma unroll
        for (int kk = 0; kk < 2; ++kk) {
            const int gb = kk * 4 + lq;
            s16x8 a1f[4], a2f[4], b1f[4], b2f[4];
#pragma unroll
            for (int i = 0; i < 4; ++i) {
                const int ra = wm + i * 16 + lp;
                a1f[i] = *(const s16x8*)&A1[swz8(ra, gb)];
                a2f[i] = *(const s16x8*)&A2[swz8(ra, gb)];
                const int rb = wn + i * 16 + lp;
                b1f[i] = *(const s16x8*)&B1[swz8(rb, gb)];
                b2f[i] = *(const s16x8*)&B2[swz8(rb, gb)];
            }
#pragma unroll
            for (int i = 0; i < 4; ++i)
#pragma unroll
                for (int j = 0; j < 4; ++j) {
                    acc[i][j] = __builtin_amdgcn_mfma_f32_16x16x32_bf16(
                        a1f[i], b1f[j], acc[i][j], 0, 0, 0);
                    acc[i][j] = __builtin_amdgcn_mfma_f32_16x16x32_bf16(
                        a2f[i], b1f[j], acc[i][j], 0, 0, 0);
                    acc[i][j] = __builtin_amdgcn_mfma_f32_16x16x32_bf16(
                        a1f[i], b2f[j], acc[i][j], 0, 0, 0);
                }
        }
    }

    const int crow = lq * 4, ccol = lp;
#pragma unroll
    for (int i = 0; i < 4; ++i)
#pragma unroll
        for (int j = 0; j < 4; ++j) {
            const size_t mbase = (size_t)(m0 + wm + i * 16 + crow);
            const int o = n0 + wn + j * 16 + ccol;
#pragma unroll
            for (int reg = 0; reg < 4; ++reg)
                cur[(mbase + reg) * OUT_ + o] = acc[i][j][reg];
        }
}

// LIF recurrence over T in fp64 (fallback path only)
__global__ __launch_bounds__(256)
void lif_pass(const float* __restrict__ fcb, float* __restrict__ out)
{
    const int idx = blockIdx.x * 256 + threadIdx.x;   // b*OUT + o
    const int o = idx & (OUT_ - 1);
    const double bias = (double)fcb[o];
    double v = 0.0; int cnt = 0; bool fl = false;
#pragma unroll
    for (int t = 0; t < T_; ++t) {
        const size_t p = (size_t)t * CNT_SZ + idx;
        double c = (double)out[p] + bias;
        v = v + (c - v) * 0.5;
        double d = v - 1.0;
        bool s = d >= 0.0;
        if (fabs(d) < TOL) fl = true;
        out[p] = s ? 1.0f : 0.0f;
        cnt += s ? 1 : 0;
        if (s) v = 0.0;
    }
    out[SPK_SZ + idx] = (float)cnt;
    if (fl) {
        unsigned int pI = atomicAdd(&g_ctr, 1u);
        if (pI < MAXFLAG) g_list[pI] = (unsigned int)idx;
    }
}

// fp64 recompute of flagged neurons (one wave per neuron)
__global__ void fixup(const float* __restrict__ x, const float* __restrict__ w,
                      const float* __restrict__ fcb, float* __restrict__ out)
{
    int nf = (int)g_ctr; if (nf > MAXFLAG) nf = MAXFLAG;
    const int lane = threadIdx.x & 63;
    const int wid  = (blockIdx.x * blockDim.x + threadIdx.x) >> 6;
    const int nw   = (gridDim.x * blockDim.x) >> 6;

    for (int i = wid; i < nf; i += nw) {
        unsigned int e = g_list[i];
        int b = (int)(e >> 11), o = (int)(e & (OUT_ - 1));
        double part[T_];
#pragma unroll
        for (int t = 0; t < T_; ++t) part[t] = 0.0;
        const float* wrow = w + (size_t)o * IN_;
        for (int k = lane; k < IN_; k += 64) {
            double wvv = (double)wrow[k];
#pragma unroll
            for (int t = 0; t < T_; ++t)
                part[t] = fma((double)x[((size_t)t * B_ + b) * IN_ + k], wvv, part[t]);
        }
#pragma unroll
        for (int t = 0; t < T_; ++t)
#pragma unroll
            for (int off = 32; off > 0; off >>= 1)
                part[t] += __shfl_xor(part[t], off, 64);
        if (lane == 0) {
            double bias = (double)fcb[o];
            double v = 0.0; int cnt = 0;
#pragma unroll
            for (int t = 0; t < T_; ++t) {
                double c = part[t] + bias;
                v = v + (c - v) * 0.5;
                bool s = (v - 1.0) >= 0.0;
                out[(size_t)t * CNT_SZ + (size_t)b * OUT_ + o] = s ? 1.0f : 0.0f;
                cnt += s ? 1 : 0;
                if (s) v = 0.0;
            }
            out[SPK_SZ + (size_t)b * OUT_ + o] = (float)cnt;
        }
    }
}

// logits[b][c] = sum_o count[b][o] * aux_w[c][o] + aux_b[c]
__global__ void aux_logits(const float* __restrict__ cnt,
                           const float* __restrict__ aw,
                           const float* __restrict__ ab,
                           float* __restrict__ lg)
{
    const int b = blockIdx.x;
    const int lane = threadIdx.x;  // 64 threads = 1 wave
    double p0=0,p1=0,p2=0,p3=0,p4=0,p5=0,p6=0,p7=0,p8=0,p9=0;
    for (int o = lane; o < OUT_; o += 64) {
        double c = (double)cnt[(size_t)b * OUT_ + o];
        p0 = fma(c, (double)aw[0 * OUT_ + o], p0);
        p1 = fma(c, (double)aw[1 * OUT_ + o], p1);
        p2 = fma(c, (double)aw[2 * OUT_ + o], p2);
        p3 = fma(c, (double)aw[3 * OUT_ + o], p3);
        p4 = fma(c, (double)aw[4 * OUT_ + o], p4);
        p5 = fma(c, (double)aw[5 * OUT_ + o], p5);
        p6 = fma(c, (double)aw[6 * OUT_ + o], p6);
        p7 = fma(c, (double)aw[7 * OUT_ + o], p7);
        p8 = fma(c, (double)aw[8 * OUT_ + o], p8);
        p9 = fma(c, (double)aw[9 * OUT_ + o], p9);
    }
#pragma unroll
    for (int off = 32; off > 0; off >>= 1) {
        p0 += __shfl_xor(p0, off, 64); p1 += __shfl_xor(p1, off, 64);
        p2 += __shfl_xor(p2, off, 64); p3 += __shfl_xor(p3, off, 64);
        p4 += __shfl_xor(p4, off, 64); p5 += __shfl_xor(p5, off, 64);
        p6 += __shfl_xor(p6, off, 64); p7 += __shfl_xor(p7, off, 64);
        p8 += __shfl_xor(p8, off, 64); p9 += __shfl_xor(p9, off, 64);
    }
    if (lane == 0) {
        double pv[NC_] = {p0,p1,p2,p3,p4,p5,p6,p7,p8,p9};
#pragma unroll
        for (int c = 0; c < NC_; ++c)
            lg[(size_t)b * NC_ + c] = (float)(pv[c] + (double)ab[c]);
    }
}

extern "C" void kernel_launch(void* const* d_in, const int* in_sizes, int n_in,
                              void* d_out, int out_size, void* d_ws, size_t ws_size,
                              hipStream_t stream)
{
    (void)in_sizes; (void)n_in; (void)out_size;
    const float* x   = (const float*)d_in[0];
    const float* w   = (const float*)d_in[1];
    const float* fcb = (const float*)d_in[2];
    const float* aw  = (const float*)d_in[3];
    const float* ab  = (const float*)d_in[4];
    float* out = (float*)d_out;

    const size_t needA = (size_t)APAN * NCH2 * TILE_US * 2;  // 100.7 MB
    const size_t needB = (size_t)BPAN * NCH2 * TILE_US * 2;  // 25.2 MB

    if (ws_size >= needA + needB) {
        unsigned short* Adig = (unsigned short*)d_ws;
        unsigned short* Bdig = Adig + (size_t)APAN * NCH2 * TILE_US;
        prep2<<<dim3(A_PREP_BLOCKS + B_PREP_BLOCKS), dim3(256), 0, stream>>>(
            x, w, Adig, Bdig);
        gemm_fused<<<dim3(256), dim3(512), 0, stream>>>(Adig, Bdig, fcb, out);
    } else {
        zero_ctr<<<dim3(1), dim3(64), 0, stream>>>();
        gemm_split<<<dim3(M_ / BM, OUT_ / BN), dim3(256), 0, stream>>>(x, w, out);
        lif_pass<<<dim3(CNT_SZ / 256), dim3(256), 0, stream>>>(fcb, out);
    }

    fixup<<<dim3(192), dim3(256), 0, stream>>>(x, w, fcb, out);

    aux_logits<<<dim3(B_), dim3(64), 0, stream>>>(
        out + SPK_SZ, aw, ab, out + SPK_SZ + CNT_SZ);
}